// Round 18
// baseline (148.673 us; speedup 1.0000x reference)
//
#include <hip/hip_runtime.h>

#define B_ 2
#define T_ 2048
#define C_ 1024
#define H_ 16
#define HD_ 1024
#define QLD 3072  // fused qkv row stride
#define LOG2E 1.4426950408889634f

typedef unsigned short u16;
typedef short bf16x8 __attribute__((ext_vector_type(8)));
typedef float f32x4 __attribute__((ext_vector_type(4)));
typedef float f32x16 __attribute__((ext_vector_type(16)));
typedef u16 u16x8 __attribute__((ext_vector_type(8)));

__device__ __forceinline__ u16 f2bf(float f) {
  unsigned u = __float_as_uint(f);
  u += 0x7FFFu + ((u >> 16) & 1u);
  return (u16)(u >> 16);
}
__device__ __forceinline__ float bf2f(u16 h) { return __uint_as_float(((unsigned)h) << 16); }

__device__ __forceinline__ unsigned cvt_pk_bf16(float lo, float hi) {
  unsigned r;
  asm("v_cvt_pk_bf16_f32 %0, %1, %2" : "=v"(r) : "v"(lo), "v"(hi));
  return r;
}
__device__ __forceinline__ float fexp2(float x) {
  float r;
  asm("v_exp_f32 %0, %1" : "=v"(r) : "v"(x));
  return r;
}

__device__ __forceinline__ void gload16(const void* g, void* l) {
  __builtin_amdgcn_global_load_lds(
      (const __attribute__((address_space(1))) unsigned int*)g,
      (__attribute__((address_space(3))) unsigned int*)l, 16, 0, 0);
}

#define VM_WAIT(n) asm volatile("s_waitcnt vmcnt(" #n ")" ::: "memory")
#define BAR() asm volatile("s_barrier" ::: "memory")
#define PRIO(n) __builtin_amdgcn_s_setprio(n)

#define MFMA16(a, b, c) __builtin_amdgcn_mfma_f32_16x16x32_bf16((a), (b), (c), 0, 0, 0)
#define MFMA32(a, b, c) __builtin_amdgcn_mfma_f32_32x32x16_bf16((a), (b), (c), 0, 0, 0)

// ---- prep ---------------------------------------------------------------
__global__ void prep_kernel(const float* ps, const float* wmod, const float* bmod,
                            float* out_tail, float* scale_buf, float* diag_buf) {
  int t = threadIdx.x;
  if (t < B_ * H_) {
    int b = t >> 4, h = t & 15;
    float p = ps[b];
    float m0 = p * wmod[2 * h] + bmod[2 * h];
    float m1 = p * wmod[2 * h + 1] + bmod[2 * h + 1];
    float sp = (m0 > 20.f) ? m0 : log1pf(expf(m0));
    float temp = 1.f + sp;
    out_tail[t] = temp;                  // temp_scale output
    scale_buf[t] = LOG2E / (8.f * temp); // folded into q at gemm epilogue
    diag_buf[t] = m1 * LOG2E;
  }
}

// ---- x: f32 -> bf16 ------------------------------------------------------
__global__ void convert_x(const float* __restrict__ x, u16* __restrict__ xb) {
  int i = blockIdx.x * 256 + threadIdx.x;
  float4 v = ((const float4*)x)[i];
  ushort4 o;
  o.x = f2bf(v.x); o.y = f2bf(v.y); o.z = f2bf(v.z); o.w = f2bf(v.w);
  ((ushort4*)xb)[i] = o;
}

// ---- weights: f32 [K][N] -> bf16 transposed; q,k,v fused [3072][1024] ----
__global__ void convert_w_t(const float* wq, const float* wk, const float* wv,
                            const float* wo, u16* qkvT, u16* woT) {
  int z = blockIdx.z;
  const float* w = (z == 0) ? wq : (z == 1) ? wk : (z == 2) ? wv : wo;
  u16* wt = (z == 3) ? woT : qkvT + (size_t)z * 1024 * 1024;
  __shared__ float tile[64][65];
  int k0 = blockIdx.x * 64, n0 = blockIdx.y * 64;
  int tid = threadIdx.x;
  int r = tid >> 4, c = (tid & 15) * 4;
#pragma unroll
  for (int i = 0; i < 4; i++) {
    float4 v = *(const float4*)(w + (size_t)(k0 + r + i * 16) * 1024 + n0 + c);
    tile[r + i * 16][c] = v.x; tile[r + i * 16][c + 1] = v.y;
    tile[r + i * 16][c + 2] = v.z; tile[r + i * 16][c + 3] = v.w;
  }
  __syncthreads();
#pragma unroll
  for (int i = 0; i < 4; i++) {
    int rn = r + i * 16;
    ushort4 o;
    o.x = f2bf(tile[c][rn]); o.y = f2bf(tile[c + 1][rn]);
    o.z = f2bf(tile[c + 2][rn]); o.w = f2bf(tile[c + 3][rn]);
    *(ushort4*)(wt + (size_t)(n0 + rn) * 1024 + k0 + c) = o;
  }
}

// ---- fused QKV GEMM (ring-3, 2-barrier, counted vmcnt, XCD swizzle) ------
// grid: 1-D, 768 blocks = 32 m-tiles x 24 n-tiles
__global__ __launch_bounds__(256) void gemm_qkv(const u16* __restrict__ A, const u16* __restrict__ BT,
                                                const float* __restrict__ bq, const float* __restrict__ bk,
                                                const float* __restrict__ bv,
                                                const float* __restrict__ scale_buf,
                                                u16* __restrict__ Cout) {
  __shared__ u16 As[3][128 * 32];
  __shared__ u16 Bs[3][128 * 32];
  // XCD-aware bijective swizzle (768 % 8 == 0): each XCD gets a contiguous
  // 96-block chunk -> B-panel reuse lands in the same per-XCD L2.
  int bid = blockIdx.x;
  int nbid = (bid & 7) * 96 + (bid >> 3);
  int m0 = (nbid & 31) * 128, n0 = (nbid >> 5) * 128;
  int tid = threadIdx.x;
  int w = tid >> 6, l = tid & 63;
  int wr = w >> 1, wc = w & 1;
  int lrow = l & 15, kb = l >> 4;
  int r = tid >> 2, c = tid & 3;
  f32x4 acc[4][4] = {};

#define GQ_STAGE(buf, k0g)                                                                  \
  {                                                                                         \
    _Pragma("unroll") for (int j = 0; j < 2; j++) {                                         \
      gload16(A + (size_t)(m0 + r + j * 64) * C_ + (k0g) + c * 8,                           \
              (char*)As[buf] + (r + j * 64) * 64 + c * 16);                                 \
      gload16(BT + (size_t)(n0 + r + j * 64) * C_ + (k0g) + c * 8,                          \
              (char*)Bs[buf] + (r + j * 64) * 64 + c * 16);                                 \
    }                                                                                       \
  }

#define GQ_COMPUTE(BUF)                                                                     \
  {                                                                                         \
    const u16* Ac = As[BUF];                                                                \
    const u16* Bc = Bs[BUF];                                                                \
    bf16x8 af[4], bfv[4];                                                                   \
    _Pragma("unroll") for (int mi = 0; mi < 4; mi++)                                        \
        af[mi] = *(const bf16x8*)(Ac + (wr * 64 + mi * 16 + lrow) * 32 + kb * 8);           \
    _Pragma("unroll") for (int ni = 0; ni < 4; ni++)                                        \
        bfv[ni] = *(const bf16x8*)(Bc + (wc * 64 + ni * 16 + lrow) * 32 + kb * 8);          \
    _Pragma("unroll") for (int mi = 0; mi < 4; mi++)                                        \
        _Pragma("unroll") for (int ni = 0; ni < 4; ni++)                                    \
            acc[mi][ni] = MFMA16(af[mi], bfv[ni], acc[mi][ni]);                             \
  }

  GQ_STAGE(0, 0);
  GQ_STAGE(1, 32);
  int buf = 0;
  for (int i = 0; i < 30; i++) {
    int nbuf = (buf + 2) % 3;
    GQ_STAGE(nbuf, (i + 2) * 32);
    VM_WAIT(8);
    BAR();
    GQ_COMPUTE(buf);
    BAR();
    buf = (buf + 1) % 3;
  }
  VM_WAIT(4);
  BAR();
  GQ_COMPUTE(buf);
  buf = (buf + 1) % 3;
  VM_WAIT(0);
  BAR();
  GQ_COMPUTE(buf);
#undef GQ_STAGE
#undef GQ_COMPUTE

  int bb = m0 >> 11;
#pragma unroll
  for (int mi = 0; mi < 4; mi++)
#pragma unroll
    for (int ni = 0; ni < 4; ni++) {
      int gcol = n0 + wc * 64 + ni * 16 + lrow;
      int sect = gcol >> 10;
      const float* bp = (sect == 0) ? bq : (sect == 1) ? bk : bv;
      float bvf = bp[gcol & 1023];
      float fac = (sect == 0) ? scale_buf[bb * 16 + ((gcol >> 6) & 15)] : 1.f;
#pragma unroll
      for (int rr = 0; rr < 4; rr++) {
        int grow = m0 + wr * 64 + mi * 16 + kb * 4 + rr;
        Cout[(size_t)grow * QLD + gcol] = f2bf((acc[mi][ni][rr] + bvf) * fac);
      }
    }
}

// ---- out-projection GEMM (ring-3, 2-barrier, XCD swizzle), f32 out -------
// grid: 1-D, 256 blocks = 32 m-tiles x 8 n-tiles
__global__ __launch_bounds__(256) void gemm_bt_f32(const u16* __restrict__ A, const u16* __restrict__ BT,
                                                   const float* __restrict__ bias,
                                                   float* __restrict__ Cout) {
  __shared__ u16 As[3][128 * 32];
  __shared__ u16 Bs[3][128 * 32];
  int bid = blockIdx.x;
  int nbid = (bid & 7) * 32 + (bid >> 3);
  int m0 = (nbid & 31) * 128, n0 = (nbid >> 5) * 128;
  int tid = threadIdx.x;
  int w = tid >> 6, l = tid & 63;
  int wr = w >> 1, wc = w & 1;
  int lrow = l & 15, kb = l >> 4;
  int r = tid >> 2, c = tid & 3;
  f32x4 acc[4][4] = {};

#define GB_STAGE(buf, k0g)                                                                  \
  {                                                                                         \
    _Pragma("unroll") for (int j = 0; j < 2; j++) {                                         \
      gload16(A + (size_t)(m0 + r + j * 64) * C_ + (k0g) + c * 8,                           \
              (char*)As[buf] + (r + j * 64) * 64 + c * 16);                                 \
      gload16(BT + (size_t)(n0 + r + j * 64) * C_ + (k0g) + c * 8,                          \
              (char*)Bs[buf] + (r + j * 64) * 64 + c * 16);                                 \
    }                                                                                       \
  }

#define GB_COMPUTE(BUF)                                                                     \
  {                                                                                         \
    const u16* Ac = As[BUF];                                                                \
    const u16* Bc = Bs[BUF];                                                                \
    bf16x8 af[4], bfv[4];                                                                   \
    _Pragma("unroll") for (int mi = 0; mi < 4; mi++)                                        \
        af[mi] = *(const bf16x8*)(Ac + (wr * 64 + mi * 16 + lrow) * 32 + kb * 8);           \
    _Pragma("unroll") for (int ni = 0; ni < 4; ni++)                                        \
        bfv[ni] = *(const bf16x8*)(Bc + (wc * 64 + ni * 16 + lrow) * 32 + kb * 8);          \
    _Pragma("unroll") for (int mi = 0; mi < 4; mi++)                                        \
        _Pragma("unroll") for (int ni = 0; ni < 4; ni++)                                    \
            acc[mi][ni] = MFMA16(af[mi], bfv[ni], acc[mi][ni]);                             \
  }

  GB_STAGE(0, 0);
  GB_STAGE(1, 32);
  int buf = 0;
  for (int i = 0; i < 30; i++) {
    int nbuf = (buf + 2) % 3;
    GB_STAGE(nbuf, (i + 2) * 32);
    VM_WAIT(8);
    BAR();
    GB_COMPUTE(buf);
    BAR();
    buf = (buf + 1) % 3;
  }
  VM_WAIT(4);
  BAR();
  GB_COMPUTE(buf);
  buf = (buf + 1) % 3;
  VM_WAIT(0);
  BAR();
  GB_COMPUTE(buf);
#undef GB_STAGE
#undef GB_COMPUTE

#pragma unroll
  for (int mi = 0; mi < 4; mi++)
#pragma unroll
    for (int ni = 0; ni < 4; ni++) {
      int gcol = n0 + wc * 64 + ni * 16 + lrow;
      float bvf = bias[gcol];
#pragma unroll
      for (int rr = 0; rr < 4; rr++) {
        int grow = m0 + wr * 64 + mi * 16 + kb * 4 + rr;
        Cout[(size_t)grow * C_ + gcol] = acc[mi][ni][rr] + bvf;
      }
    }
}

// ---- pass 1: partial l[s] (8 waves, ring-4 Q prefetch, counted vmcnt) ----
__global__ __launch_bounds__(512) void attn_pass1(const u16* __restrict__ q, const u16* __restrict__ k,
                                                  const int* __restrict__ mask,
                                                  const float* __restrict__ diag_buf,
                                                  float* __restrict__ l_part) {
  __shared__ u16 Qs[4][64 * 64];
  int bh = blockIdx.x, b = bh >> 4, h = bh & 15;
  int s0b = blockIdx.y * 256;
  int half = blockIdx.z;
  int tid = threadIdx.x, w = tid >> 6, l = tid & 63;
  int lane31 = l & 31, hi = l >> 5;
  float diagb = diag_buf[bh];
  int s_wb = s0b + w * 32;
  int s_g = s_wb + lane31;
  bool dhit = (((l >> 2) & 1) == hi);
  int dreg = (l & 3) + 4 * ((l >> 3) & 3);
  int sr = tid >> 3, slotL = tid & 7;
  int slotG = slotL ^ (sr & 7);
  bf16x8 kf[4];
#pragma unroll
  for (int ks = 0; ks < 4; ks++)
    kf[ks] = *(const bf16x8*)(k + (size_t)(b * T_ + s_g) * QLD + h * 64 + ks * 16 + hi * 8);

  int tbase = half * 1024;
#define STAGE_Q(buf, t0g)                                                     \
  gload16(q + (size_t)(b * T_ + (t0g) + sr) * QLD + h * 64 + slotG * 8,       \
          (char*)Qs[buf] + sr * 128 + slotL * 16)

#define P1_COMPUTE(IT)                                                        \
  {                                                                           \
    const u16* Qc = Qs[(IT) & 3];                                             \
    int t0 = tbase + (IT) * 64;                                               \
    _Pragma("unroll") for (int sub = 0; sub < 2; sub++) {                     \
      int tloc = sub * 32;                                                    \
      f32x16 sacc = {};                                                       \
      PRIO(1);                                                                \
      _Pragma("unroll") for (int ks = 0; ks < 4; ks++) {                      \
        int row = tloc + lane31;                                              \
        int slot = (ks * 2 + hi) ^ (row & 7);                                 \
        bf16x8 qa = *(const bf16x8*)(Qc + row * 64 + slot * 8);               \
        sacc = MFMA32(qa, kf[ks], sacc);                                      \
      }                                                                       \
      PRIO(0);                                                                \
      if (t0 + tloc == s_wb) {                                                \
        _Pragma("unroll") for (int r = 0; r < 16; r++)                        \
            sacc[r] += (dhit && r == dreg) ? diagb : 0.f;                     \
      }                                                                       \
      int mv = mask[b * T_ + t0 + tloc + lane31];                             \
      bool allset = (~__ballot(mv != 0)) == 0ull;                             \
      if (allset) {                                                           \
        _Pragma("unroll") for (int r = 0; r < 16; r++) lsum += fexp2(sacc[r]); \
      } else {                                                                \
        float mvf = mv ? 1.f : 0.f;                                           \
        _Pragma("unroll") for (int r = 0; r < 16; r++) {                      \
          float mp = __shfl(mvf, (r & 3) + 8 * (r >> 2) + 4 * hi, 64);        \
          lsum += mp * fexp2(sacc[r]);                                        \
        }                                                                     \
      }                                                                       \
    }                                                                         \
  }

  float lsum = 0.f;
  STAGE_Q(0, tbase);
  STAGE_Q(1, tbase + 64);
  for (int it = 0; it < 14; it++) {
    STAGE_Q((it + 2) & 3, tbase + (it + 2) * 64);
    VM_WAIT(2);
    BAR();
    P1_COMPUTE(it);
  }
  VM_WAIT(1);
  BAR();
  P1_COMPUTE(14);
  VM_WAIT(0);
  BAR();
  P1_COMPUTE(15);
  float total = lsum + __shfl_xor(lsum, 32, 64);
  if (hi == 0) l_part[half * (32 * 2048) + bh * 2048 + s_g] = total;
#undef STAGE_Q
#undef P1_COMPUTE
}

// ---- v scaled by 1/l, transposed -> vT -----------------------------------
__global__ void scale_transpose_v(const u16* __restrict__ qkv, const float* __restrict__ l_part,
                                  u16* __restrict__ vT) {
  __shared__ float tile[64][65];
  int st0 = blockIdx.x * 64;
  int hd0 = blockIdx.y * 64;
  int tid = threadIdx.x;
  int r = tid >> 4, c4 = (tid & 15) * 4;
#pragma unroll
  for (int i = 0; i < 4; i++) {
    int row = r + i * 16;
    ushort4 hh = *(const ushort4*)(qkv + (size_t)(st0 + row) * QLD + 2048 + hd0 + c4);
    tile[row][c4] = bf2f(hh.x); tile[row][c4 + 1] = bf2f(hh.y);
    tile[row][c4 + 2] = bf2f(hh.z); tile[row][c4 + 3] = bf2f(hh.w);
  }
  __syncthreads();
  int b = st0 >> 11, sbase = st0 & 2047, h = hd0 >> 6, bh = b * 16 + h;
#pragma unroll
  for (int i = 0; i < 4; i++) {
    int dl = r + i * 16;
    ushort4 o4;
#pragma unroll
    for (int j = 0; j < 4; j++) {
      int s = sbase + c4 + j;
      float il = 1.f / (l_part[bh * 2048 + s] + l_part[32 * 2048 + bh * 2048 + s]);
      ((u16*)&o4)[j] = f2bf(tile[c4 + j][dl] * il);
    }
    *(ushort4*)(vT + (size_t)(bh * 64 + dl) * T_ + sbase + c4) = o4;
  }
}

// ---- pass 2 (8 waves, s-split x2, ring-4 K/V, counted vmcnt, setprio) ----
__global__ __launch_bounds__(512) void attn_pass2(const u16* __restrict__ q, const u16* __restrict__ k,
                                                  const u16* __restrict__ vT,
                                                  const int* __restrict__ mask,
                                                  const float* __restrict__ diag_buf,
                                                  u16* __restrict__ obp) {
  __shared__ u16 Ks[4][64 * 64];
  __shared__ u16 Vs[4][64 * 64];
  int bh = blockIdx.x, b = bh >> 4, h = bh & 15;
  int t0 = blockIdx.y * 256;
  int shalf = blockIdx.z;
  int s_start = shalf * 1024;
  u16* op = obp + (size_t)shalf * 4096 * 1024;
  int tid = threadIdx.x, w = tid >> 6, l = tid & 63;
  int lane31 = l & 31, hi = l >> 5;
  float diagb = diag_buf[bh];
  int t_wb = t0 + w * 32;
  int t_g = t_wb + lane31;
  bool dhit = (((l >> 2) & 1) == hi);
  int dreg = (l & 3) + 4 * ((l >> 3) & 3);
  int sr = tid >> 3, slotL = tid & 7;
  int slotG = slotL ^ (sr & 7);
  bf16x8 qf[4];
#pragma unroll
  for (int ks = 0; ks < 4; ks++)
    qf[ks] = *(const bf16x8*)(q + (size_t)(b * T_ + t_g) * QLD + h * 64 + ks * 16 + hi * 8);
  int mv = mask[b * T_ + t_g];
  float tmf = mv ? 1.f : 0.f;
  bool allset = (~__ballot(mv != 0)) == 0ull;
  f32x16 oacc0 = {}, oacc1 = {};

#define STAGE_KV(buf, s0g)                                                    \
  {                                                                           \
    gload16(k + (size_t)(b * T_ + (s0g) + sr) * QLD + h * 64 + slotG * 8,     \
            (char*)Ks[buf] + sr * 128 + slotL * 16);                          \
    gload16(vT + (size_t)(bh * 64 + sr) * T_ + (s0g) + slotG * 8,             \
            (char*)Vs[buf] + sr * 128 + slotL * 16);                          \
  }

#define P2_COMPUTE(SI)                                                        \
  {                                                                           \
    const u16* Kc = Ks[(SI) & 3];                                             \
    const u16* Vc = Vs[(SI) & 3];                                             \
    int s0 = s_start + (SI) * 64;                                             \
    _Pragma("unroll") for (int sub = 0; sub < 2; sub++) {                     \
      int ss = sub * 32;                                                      \
      f32x16 sacc = {};                                                       \
      PRIO(1);                                                                \
      _Pragma("unroll") for (int ks = 0; ks < 4; ks++) {                      \
        int row = ss + lane31;                                                \
        int slot = (ks * 2 + hi) ^ (row & 7);                                 \
        bf16x8 kfr = *(const bf16x8*)(Kc + row * 64 + slot * 8);              \
        sacc = MFMA32(kfr, qf[ks], sacc);                                     \
      }                                                                       \
      PRIO(0);                                                                \
      if (s0 + ss == t_wb) {                                                  \
        _Pragma("unroll") for (int r = 0; r < 16; r++)                        \
            sacc[r] += (dhit && r == dreg) ? diagb : 0.f;                     \
      }                                                                       \
      float p[16];                                                            \
      _Pragma("unroll") for (int r = 0; r < 16; r++) p[r] = fexp2(sacc[r]);   \
      if (!allset) {                                                          \
        _Pragma("unroll") for (int r = 0; r < 16; r++) p[r] *= tmf;           \
      }                                                                       \
      unsigned pk[8];                                                         \
      _Pragma("unroll") for (int i = 0; i < 8; i++)                           \
          pk[i] = cvt_pk_bf16(p[2 * i], p[2 * i + 1]);                        \
      _Pragma("unroll") for (int ps = 0; ps < 2; ps++) {                      \
        unsigned a0 = pk[4 * ps + 0], a2 = pk[4 * ps + 2];                    \
        unsigned a1 = pk[4 * ps + 1], a3 = pk[4 * ps + 3];                    \
        asm("v_permlane32_swap_b32 %0, %1" : "+v"(a0), "+v"(a2));             \
        asm("v_permlane32_swap_b32 %0, %1" : "+v"(a1), "+v"(a3));             \
        union { unsigned u[4]; bf16x8 v; } fr;                                \
        fr.u[0] = a0; fr.u[1] = a1; fr.u[2] = a2; fr.u[3] = a3;               \
        PRIO(1);                                                              \
        _Pragma("unroll") for (int dh = 0; dh < 2; dh++) {                    \
          int row = dh * 32 + lane31;                                         \
          int slot = ((ss >> 3) + ps * 2 + hi) ^ (row & 7);                   \
          bf16x8 vfr = *(const bf16x8*)(Vc + row * 64 + slot * 8);            \
          if (dh == 0) oacc0 = MFMA32(fr.v, vfr, oacc0);                      \
          else oacc1 = MFMA32(fr.v, vfr, oacc1);                              \
        }                                                                     \
        PRIO(0);                                                              \
      }                                                                       \
    }                                                                         \
  }

  STAGE_KV(0, s_start);
  STAGE_KV(1, s_start + 64);
  for (int si = 0; si < 14; si++) {
    STAGE_KV((si + 2) & 3, s_start + (si + 2) * 64);
    VM_WAIT(4);
    BAR();
    P2_COMPUTE(si);
  }
  VM_WAIT(2);
  BAR();
  P2_COMPUTE(14);
  VM_WAIT(0);
  BAR();
  P2_COMPUTE(15);
#pragma unroll
  for (int r = 0; r < 16; r++) {
    int t_out = t0 + w * 32 + ((r & 3) + 8 * (r >> 2) + 4 * hi);
    size_t base = (size_t)(b * T_ + t_out) * HD_ + h * 64;
    op[base + lane31] = f2bf(oacc0[r]);
    op[base + 32 + lane31] = f2bf(oacc1[r]);
  }
#undef STAGE_KV
#undef P2_COMPUTE
}

// ---- merge the two s-half partial O buffers ------------------------------
__global__ void merge_o(const u16* __restrict__ p0, const u16* __restrict__ p1,
                        u16* __restrict__ ob) {
  int i = blockIdx.x * 256 + threadIdx.x;
  u16x8 a = ((const u16x8*)p0)[i];
  u16x8 b = ((const u16x8*)p1)[i];
  u16x8 o;
#pragma unroll
  for (int j = 0; j < 8; j++) o[j] = f2bf(bf2f(a[j]) + bf2f(b[j]));
  ((u16x8*)ob)[i] = o;
}

extern "C" void kernel_launch(void* const* d_in, const int* in_sizes, int n_in,
                              void* d_out, int out_size, void* d_ws, size_t ws_size,
                              hipStream_t stream) {
  const float* x = (const float*)d_in[0];
  const int* mask = (const int*)d_in[1];
  const float* ps = (const float*)d_in[2];
  const float* wq = (const float*)d_in[3];
  const float* bq = (const float*)d_in[4];
  const float* wk = (const float*)d_in[5];
  const float* bk = (const float*)d_in[6];
  const float* wv = (const float*)d_in[7];
  const float* bv = (const float*)d_in[8];
  const float* wmod = (const float*)d_in[9];
  const float* bmod = (const float*)d_in[10];
  const float* wo = (const float*)d_in[11];
  const float* bo = (const float*)d_in[12];
  float* out = (float*)d_out;

  const size_t MB = 1ull << 20;
  char* ws = (char*)d_ws;
  u16* xb    = (u16*)(ws + 0 * MB);   // 8 MB
  u16* qkvT  = (u16*)(ws + 8 * MB);   // 6 MB
  u16* woT   = (u16*)(ws + 14 * MB);  // 2 MB
  u16* qkv   = (u16*)(ws + 16 * MB);  // 24 MB
  u16* vT    = (u16*)(ws + 40 * MB);  // 8 MB
  u16* ob    = (u16*)(ws + 48 * MB);  // 8 MB
  float* l_part    = (float*)(ws + 56 * MB);            // 512 KB
  float* scale_buf = (float*)(ws + 56 * MB + 0x80000);  // 128 B
  float* diag_buf  = (float*)(ws + 56 * MB + 0x80100);  // 128 B
  u16* obp   = (u16*)(ws + 64 * MB);  // 16 MB (2 x 8 MB partial O)

  prep_kernel<<<1, 64, 0, stream>>>(ps, wmod, bmod, out + (size_t)B_ * T_ * C_, scale_buf, diag_buf);
  convert_x<<<4096, 256, 0, stream>>>(x, xb);
  convert_w_t<<<dim3(16, 16, 4), 256, 0, stream>>>(wq, wk, wv, wo, qkvT, woT);
  gemm_qkv<<<768, 256, 0, stream>>>(xb, qkvT, bq, bk, bv, scale_buf, qkv);
  attn_pass1<<<dim3(32, 8, 2), 512, 0, stream>>>(qkv, qkv + 1024, mask, diag_buf, l_part);
  scale_transpose_v<<<dim3(64, 16), 256, 0, stream>>>(qkv, l_part, vT);
  attn_pass2<<<dim3(32, 8, 2), 512, 0, stream>>>(qkv, qkv + 1024, vT, mask, diag_buf, obp);
  merge_o<<<2048, 256, 0, stream>>>(obp, obp + (size_t)4096 * 1024, ob);
  gemm_bt_f32<<<256, 256, 0, stream>>>(ob, woT, bo, out);
}

// Round 19
// 142.281 us; speedup vs baseline: 1.0449x; 1.0449x over previous
//
#include <hip/hip_runtime.h>

#define B_ 2
#define T_ 2048
#define C_ 1024
#define H_ 16
#define HD_ 1024
#define QLD 3072  // fused qkv row stride
#define LOG2E 1.4426950408889634f

typedef unsigned short u16;
typedef short bf16x8 __attribute__((ext_vector_type(8)));
typedef float f32x4 __attribute__((ext_vector_type(4)));
typedef float f32x16 __attribute__((ext_vector_type(16)));
typedef u16 u16x8 __attribute__((ext_vector_type(8)));

__device__ __forceinline__ u16 f2bf(float f) {
  unsigned u = __float_as_uint(f);
  u += 0x7FFFu + ((u >> 16) & 1u);
  return (u16)(u >> 16);
}
__device__ __forceinline__ float bf2f(u16 h) { return __uint_as_float(((unsigned)h) << 16); }

__device__ __forceinline__ unsigned cvt_pk_bf16(float lo, float hi) {
  unsigned r;
  asm("v_cvt_pk_bf16_f32 %0, %1, %2" : "=v"(r) : "v"(lo), "v"(hi));
  return r;
}
__device__ __forceinline__ float fexp2(float x) {
  float r;
  asm("v_exp_f32 %0, %1" : "=v"(r) : "v"(x));
  return r;
}

__device__ __forceinline__ void gload16(const void* g, void* l) {
  __builtin_amdgcn_global_load_lds(
      (const __attribute__((address_space(1))) unsigned int*)g,
      (__attribute__((address_space(3))) unsigned int*)l, 16, 0, 0);
}

#define VM_WAIT(n) asm volatile("s_waitcnt vmcnt(" #n ")" ::: "memory")
#define BAR() asm volatile("s_barrier" ::: "memory")
#define PRIO(n) __builtin_amdgcn_s_setprio(n)

#define MFMA16(a, b, c) __builtin_amdgcn_mfma_f32_16x16x32_bf16((a), (b), (c), 0, 0, 0)
#define MFMA32(a, b, c) __builtin_amdgcn_mfma_f32_32x32x16_bf16((a), (b), (c), 0, 0, 0)

// ---- fused front-end: convert_x + convert_w_t + prep ---------------------
// blocks [0,4096): x f32->bf16; [4096,5120): weight transpose; 5120: prep
__global__ void prepare_all(const float* __restrict__ x, u16* __restrict__ xb,
                            const float* wq, const float* wk, const float* wv,
                            const float* wo, u16* qkvT, u16* woT,
                            const float* ps, const float* wmod, const float* bmod,
                            float* out_tail, float* scale_buf, float* diag_buf) {
  int bid = blockIdx.x;
  int tid = threadIdx.x;
  if (bid < 4096) {
    int i = bid * 256 + tid;
    float4 v = ((const float4*)x)[i];
    ushort4 o;
    o.x = f2bf(v.x); o.y = f2bf(v.y); o.z = f2bf(v.z); o.w = f2bf(v.w);
    ((ushort4*)xb)[i] = o;
    return;
  }
  if (bid < 5120) {
    int inner = bid - 4096;
    int z = inner >> 8;
    int rem = inner & 255;
    int k0 = (rem & 15) * 64, n0 = (rem >> 4) * 64;
    const float* w = (z == 0) ? wq : (z == 1) ? wk : (z == 2) ? wv : wo;
    u16* wt = (z == 3) ? woT : qkvT + (size_t)z * 1024 * 1024;
    __shared__ float tile[64][65];
    int r = tid >> 4, c = (tid & 15) * 4;
#pragma unroll
    for (int i = 0; i < 4; i++) {
      float4 v = *(const float4*)(w + (size_t)(k0 + r + i * 16) * 1024 + n0 + c);
      tile[r + i * 16][c] = v.x; tile[r + i * 16][c + 1] = v.y;
      tile[r + i * 16][c + 2] = v.z; tile[r + i * 16][c + 3] = v.w;
    }
    __syncthreads();
#pragma unroll
    for (int i = 0; i < 4; i++) {
      int rn = r + i * 16;
      ushort4 o;
      o.x = f2bf(tile[c][rn]); o.y = f2bf(tile[c + 1][rn]);
      o.z = f2bf(tile[c + 2][rn]); o.w = f2bf(tile[c + 3][rn]);
      *(ushort4*)(wt + (size_t)(n0 + rn) * 1024 + k0 + c) = o;
    }
    return;
  }
  // prep
  if (tid < B_ * H_) {
    int b = tid >> 4, h = tid & 15;
    float p = ps[b];
    float m0 = p * wmod[2 * h] + bmod[2 * h];
    float m1 = p * wmod[2 * h + 1] + bmod[2 * h + 1];
    float sp = (m0 > 20.f) ? m0 : log1pf(expf(m0));
    float temp = 1.f + sp;
    out_tail[tid] = temp;                  // temp_scale output
    scale_buf[tid] = LOG2E / (8.f * temp); // folded into q at gemm epilogue
    diag_buf[tid] = m1 * LOG2E;
  }
}

// ---- fused QKV GEMM (ring-3, 2-barrier, counted vmcnt) -------------------
__global__ __launch_bounds__(256) void gemm_qkv(const u16* __restrict__ A, const u16* __restrict__ BT,
                                                const float* __restrict__ bq, const float* __restrict__ bk,
                                                const float* __restrict__ bv,
                                                const float* __restrict__ scale_buf,
                                                u16* __restrict__ Cout) {
  __shared__ u16 As[3][128 * 32];
  __shared__ u16 Bs[3][128 * 32];
  int m0 = blockIdx.x * 128, n0 = blockIdx.y * 128;
  int tid = threadIdx.x;
  int w = tid >> 6, l = tid & 63;
  int wr = w >> 1, wc = w & 1;
  int lrow = l & 15, kb = l >> 4;
  int r = tid >> 2, c = tid & 3;
  f32x4 acc[4][4] = {};

#define GQ_STAGE(buf, k0g)                                                                  \
  {                                                                                         \
    _Pragma("unroll") for (int j = 0; j < 2; j++) {                                         \
      gload16(A + (size_t)(m0 + r + j * 64) * C_ + (k0g) + c * 8,                           \
              (char*)As[buf] + (r + j * 64) * 64 + c * 16);                                 \
      gload16(BT + (size_t)(n0 + r + j * 64) * C_ + (k0g) + c * 8,                          \
              (char*)Bs[buf] + (r + j * 64) * 64 + c * 16);                                 \
    }                                                                                       \
  }

#define GQ_COMPUTE(BUF)                                                                     \
  {                                                                                         \
    const u16* Ac = As[BUF];                                                                \
    const u16* Bc = Bs[BUF];                                                                \
    bf16x8 af[4], bfv[4];                                                                   \
    _Pragma("unroll") for (int mi = 0; mi < 4; mi++)                                        \
        af[mi] = *(const bf16x8*)(Ac + (wr * 64 + mi * 16 + lrow) * 32 + kb * 8);           \
    _Pragma("unroll") for (int ni = 0; ni < 4; ni++)                                        \
        bfv[ni] = *(const bf16x8*)(Bc + (wc * 64 + ni * 16 + lrow) * 32 + kb * 8);          \
    _Pragma("unroll") for (int mi = 0; mi < 4; mi++)                                        \
        _Pragma("unroll") for (int ni = 0; ni < 4; ni++)                                    \
            acc[mi][ni] = MFMA16(af[mi], bfv[ni], acc[mi][ni]);                             \
  }

  GQ_STAGE(0, 0);
  GQ_STAGE(1, 32);
  int buf = 0;
  for (int i = 0; i < 30; i++) {
    int nbuf = (buf + 2) % 3;
    GQ_STAGE(nbuf, (i + 2) * 32);
    VM_WAIT(8);
    BAR();
    GQ_COMPUTE(buf);
    BAR();
    buf = (buf + 1) % 3;
  }
  VM_WAIT(4);
  BAR();
  GQ_COMPUTE(buf);
  buf = (buf + 1) % 3;
  VM_WAIT(0);
  BAR();
  GQ_COMPUTE(buf);
#undef GQ_STAGE
#undef GQ_COMPUTE

  int bb = m0 >> 11;
#pragma unroll
  for (int mi = 0; mi < 4; mi++)
#pragma unroll
    for (int ni = 0; ni < 4; ni++) {
      int gcol = n0 + wc * 64 + ni * 16 + lrow;
      int sect = gcol >> 10;
      const float* bp = (sect == 0) ? bq : (sect == 1) ? bk : bv;
      float bvf = bp[gcol & 1023];
      float fac = (sect == 0) ? scale_buf[bb * 16 + ((gcol >> 6) & 15)] : 1.f;
#pragma unroll
      for (int rr = 0; rr < 4; rr++) {
        int grow = m0 + wr * 64 + mi * 16 + kb * 4 + rr;
        Cout[(size_t)grow * QLD + gcol] = f2bf((acc[mi][ni][rr] + bvf) * fac);
      }
    }
}

// ---- out-projection GEMM (ring-3, 2-barrier), K=N=1024, f32 out ----------
__global__ __launch_bounds__(256) void gemm_bt_f32(const u16* __restrict__ A, const u16* __restrict__ BT,
                                                   const float* __restrict__ bias,
                                                   float* __restrict__ Cout) {
  __shared__ u16 As[3][128 * 32];
  __shared__ u16 Bs[3][128 * 32];
  int m0 = blockIdx.x * 128, n0 = blockIdx.y * 128;
  int tid = threadIdx.x;
  int w = tid >> 6, l = tid & 63;
  int wr = w >> 1, wc = w & 1;
  int lrow = l & 15, kb = l >> 4;
  int r = tid >> 2, c = tid & 3;
  f32x4 acc[4][4] = {};

#define GB_STAGE(buf, k0g)                                                                  \
  {                                                                                         \
    _Pragma("unroll") for (int j = 0; j < 2; j++) {                                         \
      gload16(A + (size_t)(m0 + r + j * 64) * C_ + (k0g) + c * 8,                           \
              (char*)As[buf] + (r + j * 64) * 64 + c * 16);                                 \
      gload16(BT + (size_t)(n0 + r + j * 64) * C_ + (k0g) + c * 8,                          \
              (char*)Bs[buf] + (r + j * 64) * 64 + c * 16);                                 \
    }                                                                                       \
  }

#define GB_COMPUTE(BUF)                                                                     \
  {                                                                                         \
    const u16* Ac = As[BUF];                                                                \
    const u16* Bc = Bs[BUF];                                                                \
    bf16x8 af[4], bfv[4];                                                                   \
    _Pragma("unroll") for (int mi = 0; mi < 4; mi++)                                        \
        af[mi] = *(const bf16x8*)(Ac + (wr * 64 + mi * 16 + lrow) * 32 + kb * 8);           \
    _Pragma("unroll") for (int ni = 0; ni < 4; ni++)                                        \
        bfv[ni] = *(const bf16x8*)(Bc + (wc * 64 + ni * 16 + lrow) * 32 + kb * 8);          \
    _Pragma("unroll") for (int mi = 0; mi < 4; mi++)                                        \
        _Pragma("unroll") for (int ni = 0; ni < 4; ni++)                                    \
            acc[mi][ni] = MFMA16(af[mi], bfv[ni], acc[mi][ni]);                             \
  }

  GB_STAGE(0, 0);
  GB_STAGE(1, 32);
  int buf = 0;
  for (int i = 0; i < 30; i++) {
    int nbuf = (buf + 2) % 3;
    GB_STAGE(nbuf, (i + 2) * 32);
    VM_WAIT(8);
    BAR();
    GB_COMPUTE(buf);
    BAR();
    buf = (buf + 1) % 3;
  }
  VM_WAIT(4);
  BAR();
  GB_COMPUTE(buf);
  buf = (buf + 1) % 3;
  VM_WAIT(0);
  BAR();
  GB_COMPUTE(buf);
#undef GB_STAGE
#undef GB_COMPUTE

#pragma unroll
  for (int mi = 0; mi < 4; mi++)
#pragma unroll
    for (int ni = 0; ni < 4; ni++) {
      int gcol = n0 + wc * 64 + ni * 16 + lrow;
      float bvf = bias[gcol];
#pragma unroll
      for (int rr = 0; rr < 4; rr++) {
        int grow = m0 + wr * 64 + mi * 16 + kb * 4 + rr;
        Cout[(size_t)grow * C_ + gcol] = acc[mi][ni][rr] + bvf;
      }
    }
}

// ---- pass 1: partial l[s] (8 waves, ring-4 Q prefetch, counted vmcnt) ----
__global__ __launch_bounds__(512) void attn_pass1(const u16* __restrict__ q, const u16* __restrict__ k,
                                                  const int* __restrict__ mask,
                                                  const float* __restrict__ diag_buf,
                                                  float* __restrict__ l_part) {
  __shared__ u16 Qs[4][64 * 64];
  int bh = blockIdx.x, b = bh >> 4, h = bh & 15;
  int s0b = blockIdx.y * 256;
  int half = blockIdx.z;
  int tid = threadIdx.x, w = tid >> 6, l = tid & 63;
  int lane31 = l & 31, hi = l >> 5;
  float diagb = diag_buf[bh];
  int s_wb = s0b + w * 32;
  int s_g = s_wb + lane31;
  bool dhit = (((l >> 2) & 1) == hi);
  int dreg = (l & 3) + 4 * ((l >> 3) & 3);
  int sr = tid >> 3, slotL = tid & 7;
  int slotG = slotL ^ (sr & 7);
  bf16x8 kf[4];
#pragma unroll
  for (int ks = 0; ks < 4; ks++)
    kf[ks] = *(const bf16x8*)(k + (size_t)(b * T_ + s_g) * QLD + h * 64 + ks * 16 + hi * 8);

  int tbase = half * 1024;
#define STAGE_Q(buf, t0g)                                                     \
  gload16(q + (size_t)(b * T_ + (t0g) + sr) * QLD + h * 64 + slotG * 8,       \
          (char*)Qs[buf] + sr * 128 + slotL * 16)

#define P1_COMPUTE(IT)                                                        \
  {                                                                           \
    const u16* Qc = Qs[(IT) & 3];                                             \
    int t0 = tbase + (IT) * 64;                                               \
    _Pragma("unroll") for (int sub = 0; sub < 2; sub++) {                     \
      int tloc = sub * 32;                                                    \
      f32x16 sacc = {};                                                       \
      PRIO(1);                                                                \
      _Pragma("unroll") for (int ks = 0; ks < 4; ks++) {                      \
        int row = tloc + lane31;                                              \
        int slot = (ks * 2 + hi) ^ (row & 7);                                 \
        bf16x8 qa = *(const bf16x8*)(Qc + row * 64 + slot * 8);               \
        sacc = MFMA32(qa, kf[ks], sacc);                                      \
      }                                                                       \
      PRIO(0);                                                                \
      if (t0 + tloc == s_wb) {                                                \
        _Pragma("unroll") for (int r = 0; r < 16; r++)                        \
            sacc[r] += (dhit && r == dreg) ? diagb : 0.f;                     \
      }                                                                       \
      int mv = mask[b * T_ + t0 + tloc + lane31];                             \
      bool allset = (~__ballot(mv != 0)) == 0ull;                             \
      if (allset) {                                                           \
        _Pragma("unroll") for (int r = 0; r < 16; r++) lsum += fexp2(sacc[r]); \
      } else {                                                                \
        float mvf = mv ? 1.f : 0.f;                                           \
        _Pragma("unroll") for (int r = 0; r < 16; r++) {                      \
          float mp = __shfl(mvf, (r & 3) + 8 * (r >> 2) + 4 * hi, 64);        \
          lsum += mp * fexp2(sacc[r]);                                        \
        }                                                                     \
      }                                                                       \
    }                                                                         \
  }

  float lsum = 0.f;
  STAGE_Q(0, tbase);
  STAGE_Q(1, tbase + 64);
  for (int it = 0; it < 14; it++) {
    STAGE_Q((it + 2) & 3, tbase + (it + 2) * 64);
    VM_WAIT(2);
    BAR();
    P1_COMPUTE(it);
  }
  VM_WAIT(1);
  BAR();
  P1_COMPUTE(14);
  VM_WAIT(0);
  BAR();
  P1_COMPUTE(15);
  float total = lsum + __shfl_xor(lsum, 32, 64);
  if (hi == 0) l_part[half * (32 * 2048) + bh * 2048 + s_g] = total;
#undef STAGE_Q
#undef P1_COMPUTE
}

// ---- v scaled by 1/l, transposed -> vT -----------------------------------
__global__ void scale_transpose_v(const u16* __restrict__ qkv, const float* __restrict__ l_part,
                                  u16* __restrict__ vT) {
  __shared__ float tile[64][65];
  int st0 = blockIdx.x * 64;
  int hd0 = blockIdx.y * 64;
  int tid = threadIdx.x;
  int r = tid >> 4, c4 = (tid & 15) * 4;
#pragma unroll
  for (int i = 0; i < 4; i++) {
    int row = r + i * 16;
    ushort4 hh = *(const ushort4*)(qkv + (size_t)(st0 + row) * QLD + 2048 + hd0 + c4);
    tile[row][c4] = bf2f(hh.x); tile[row][c4 + 1] = bf2f(hh.y);
    tile[row][c4 + 2] = bf2f(hh.z); tile[row][c4 + 3] = bf2f(hh.w);
  }
  __syncthreads();
  int b = st0 >> 11, sbase = st0 & 2047, h = hd0 >> 6, bh = b * 16 + h;
#pragma unroll
  for (int i = 0; i < 4; i++) {
    int dl = r + i * 16;
    ushort4 o4;
#pragma unroll
    for (int j = 0; j < 4; j++) {
      int s = sbase + c4 + j;
      float il = 1.f / (l_part[bh * 2048 + s] + l_part[32 * 2048 + bh * 2048 + s]);
      ((u16*)&o4)[j] = f2bf(tile[c4 + j][dl] * il);
    }
    *(ushort4*)(vT + (size_t)(bh * 64 + dl) * T_ + sbase + c4) = o4;
  }
}

// ---- pass 2 (8 waves, s-split x2, ring-4 K/V, counted vmcnt, setprio) ----
__global__ __launch_bounds__(512) void attn_pass2(const u16* __restrict__ q, const u16* __restrict__ k,
                                                  const u16* __restrict__ vT,
                                                  const int* __restrict__ mask,
                                                  const float* __restrict__ diag_buf,
                                                  u16* __restrict__ obp) {
  __shared__ u16 Ks[4][64 * 64];
  __shared__ u16 Vs[4][64 * 64];
  int bh = blockIdx.x, b = bh >> 4, h = bh & 15;
  int t0 = blockIdx.y * 256;
  int shalf = blockIdx.z;
  int s_start = shalf * 1024;
  u16* op = obp + (size_t)shalf * 4096 * 1024;
  int tid = threadIdx.x, w = tid >> 6, l = tid & 63;
  int lane31 = l & 31, hi = l >> 5;
  float diagb = diag_buf[bh];
  int t_wb = t0 + w * 32;
  int t_g = t_wb + lane31;
  bool dhit = (((l >> 2) & 1) == hi);
  int dreg = (l & 3) + 4 * ((l >> 3) & 3);
  int sr = tid >> 3, slotL = tid & 7;
  int slotG = slotL ^ (sr & 7);
  bf16x8 qf[4];
#pragma unroll
  for (int ks = 0; ks < 4; ks++)
    qf[ks] = *(const bf16x8*)(q + (size_t)(b * T_ + t_g) * QLD + h * 64 + ks * 16 + hi * 8);
  int mv = mask[b * T_ + t_g];
  float tmf = mv ? 1.f : 0.f;
  bool allset = (~__ballot(mv != 0)) == 0ull;
  f32x16 oacc0 = {}, oacc1 = {};

#define STAGE_KV(buf, s0g)                                                    \
  {                                                                           \
    gload16(k + (size_t)(b * T_ + (s0g) + sr) * QLD + h * 64 + slotG * 8,     \
            (char*)Ks[buf] + sr * 128 + slotL * 16);                          \
    gload16(vT + (size_t)(bh * 64 + sr) * T_ + (s0g) + slotG * 8,             \
            (char*)Vs[buf] + sr * 128 + slotL * 16);                          \
  }

#define P2_COMPUTE(SI)                                                        \
  {                                                                           \
    const u16* Kc = Ks[(SI) & 3];                                             \
    const u16* Vc = Vs[(SI) & 3];                                             \
    int s0 = s_start + (SI) * 64;                                             \
    _Pragma("unroll") for (int sub = 0; sub < 2; sub++) {                     \
      int ss = sub * 32;                                                      \
      f32x16 sacc = {};                                                       \
      PRIO(1);                                                                \
      _Pragma("unroll") for (int ks = 0; ks < 4; ks++) {                      \
        int row = ss + lane31;                                                \
        int slot = (ks * 2 + hi) ^ (row & 7);                                 \
        bf16x8 kfr = *(const bf16x8*)(Kc + row * 64 + slot * 8);              \
        sacc = MFMA32(kfr, qf[ks], sacc);                                     \
      }                                                                       \
      PRIO(0);                                                                \
      if (s0 + ss == t_wb) {                                                  \
        _Pragma("unroll") for (int r = 0; r < 16; r++)                        \
            sacc[r] += (dhit && r == dreg) ? diagb : 0.f;                     \
      }                                                                       \
      float p[16];                                                            \
      _Pragma("unroll") for (int r = 0; r < 16; r++) p[r] = fexp2(sacc[r]);   \
      if (!allset) {                                                          \
        _Pragma("unroll") for (int r = 0; r < 16; r++) p[r] *= tmf;           \
      }                                                                       \
      unsigned pk[8];                                                         \
      _Pragma("unroll") for (int i = 0; i < 8; i++)                           \
          pk[i] = cvt_pk_bf16(p[2 * i], p[2 * i + 1]);                        \
      _Pragma("unroll") for (int ps = 0; ps < 2; ps++) {                      \
        unsigned a0 = pk[4 * ps + 0], a2 = pk[4 * ps + 2];                    \
        unsigned a1 = pk[4 * ps + 1], a3 = pk[4 * ps + 3];                    \
        asm("v_permlane32_swap_b32 %0, %1" : "+v"(a0), "+v"(a2));             \
        asm("v_permlane32_swap_b32 %0, %1" : "+v"(a1), "+v"(a3));             \
        union { unsigned u[4]; bf16x8 v; } fr;                                \
        fr.u[0] = a0; fr.u[1] = a1; fr.u[2] = a2; fr.u[3] = a3;               \
        PRIO(1);                                                              \
        _Pragma("unroll") for (int dh = 0; dh < 2; dh++) {                    \
          int row = dh * 32 + lane31;                                         \
          int slot = ((ss >> 3) + ps * 2 + hi) ^ (row & 7);                   \
          bf16x8 vfr = *(const bf16x8*)(Vc + row * 64 + slot * 8);            \
          if (dh == 0) oacc0 = MFMA32(fr.v, vfr, oacc0);                      \
          else oacc1 = MFMA32(fr.v, vfr, oacc1);                              \
        }                                                                     \
        PRIO(0);                                                              \
      }                                                                       \
    }                                                                         \
  }

  STAGE_KV(0, s_start);
  STAGE_KV(1, s_start + 64);
  for (int si = 0; si < 14; si++) {
    STAGE_KV((si + 2) & 3, s_start + (si + 2) * 64);
    VM_WAIT(4);
    BAR();
    P2_COMPUTE(si);
  }
  VM_WAIT(2);
  BAR();
  P2_COMPUTE(14);
  VM_WAIT(0);
  BAR();
  P2_COMPUTE(15);
#pragma unroll
  for (int r = 0; r < 16; r++) {
    int t_out = t0 + w * 32 + ((r & 3) + 8 * (r >> 2) + 4 * hi);
    size_t base = (size_t)(b * T_ + t_out) * HD_ + h * 64;
    op[base + lane31] = f2bf(oacc0[r]);
    op[base + 32 + lane31] = f2bf(oacc1[r]);
  }
#undef STAGE_KV
#undef P2_COMPUTE
}

// ---- merge the two s-half partial O buffers ------------------------------
__global__ void merge_o(const u16* __restrict__ p0, const u16* __restrict__ p1,
                        u16* __restrict__ ob) {
  int i = blockIdx.x * 256 + threadIdx.x;
  u16x8 a = ((const u16x8*)p0)[i];
  u16x8 b = ((const u16x8*)p1)[i];
  u16x8 o;
#pragma unroll
  for (int j = 0; j < 8; j++) o[j] = f2bf(bf2f(a[j]) + bf2f(b[j]));
  ((u16x8*)ob)[i] = o;
}

extern "C" void kernel_launch(void* const* d_in, const int* in_sizes, int n_in,
                              void* d_out, int out_size, void* d_ws, size_t ws_size,
                              hipStream_t stream) {
  const float* x = (const float*)d_in[0];
  const int* mask = (const int*)d_in[1];
  const float* ps = (const float*)d_in[2];
  const float* wq = (const float*)d_in[3];
  const float* bq = (const float*)d_in[4];
  const float* wk = (const float*)d_in[5];
  const float* bk = (const float*)d_in[6];
  const float* wv = (const float*)d_in[7];
  const float* bv = (const float*)d_in[8];
  const float* wmod = (const float*)d_in[9];
  const float* bmod = (const float*)d_in[10];
  const float* wo = (const float*)d_in[11];
  const float* bo = (const float*)d_in[12];
  float* out = (float*)d_out;

  const size_t MB = 1ull << 20;
  char* ws = (char*)d_ws;
  u16* xb    = (u16*)(ws + 0 * MB);   // 8 MB
  u16* qkvT  = (u16*)(ws + 8 * MB);   // 6 MB
  u16* woT   = (u16*)(ws + 14 * MB);  // 2 MB
  u16* qkv   = (u16*)(ws + 16 * MB);  // 24 MB
  u16* vT    = (u16*)(ws + 40 * MB);  // 8 MB
  u16* ob    = (u16*)(ws + 48 * MB);  // 8 MB
  float* l_part    = (float*)(ws + 56 * MB);            // 512 KB
  float* scale_buf = (float*)(ws + 56 * MB + 0x80000);  // 128 B
  float* diag_buf  = (float*)(ws + 56 * MB + 0x80100);  // 128 B
  u16* obp   = (u16*)(ws + 64 * MB);  // 16 MB (2 x 8 MB partial O)

  prepare_all<<<5121, 256, 0, stream>>>(x, xb, wq, wk, wv, wo, qkvT, woT,
                                        ps, wmod, bmod, out + (size_t)B_ * T_ * C_,
                                        scale_buf, diag_buf);
  gemm_qkv<<<dim3(32, 24), 256, 0, stream>>>(xb, qkvT, bq, bk, bv, scale_buf, qkv);
  attn_pass1<<<dim3(32, 8, 2), 512, 0, stream>>>(qkv, qkv + 1024, mask, diag_buf, l_part);
  scale_transpose_v<<<dim3(64, 16), 256, 0, stream>>>(qkv, l_part, vT);
  attn_pass2<<<dim3(32, 8, 2), 512, 0, stream>>>(qkv, qkv + 1024, vT, mask, diag_buf, obp);
  merge_o<<<2048, 256, 0, stream>>>(obp, obp + (size_t)4096 * 1024, ob);
  gemm_bt_f32<<<dim3(32, 8), 256, 0, stream>>>(ob, woT, bo, out);
}

// Round 20
// 141.609 us; speedup vs baseline: 1.0499x; 1.0047x over previous
//
#include <hip/hip_runtime.h>

#define B_ 2
#define T_ 2048
#define C_ 1024
#define H_ 16
#define HD_ 1024
#define QLD 3072  // fused qkv row stride
#define LOG2E 1.4426950408889634f

typedef unsigned short u16;
typedef short bf16x8 __attribute__((ext_vector_type(8)));
typedef float f32x4 __attribute__((ext_vector_type(4)));
typedef float f32x16 __attribute__((ext_vector_type(16)));
typedef u16 u16x8 __attribute__((ext_vector_type(8)));

__device__ __forceinline__ u16 f2bf(float f) {
  unsigned u = __float_as_uint(f);
  u += 0x7FFFu + ((u >> 16) & 1u);
  return (u16)(u >> 16);
}
__device__ __forceinline__ float bf2f(u16 h) { return __uint_as_float(((unsigned)h) << 16); }

__device__ __forceinline__ unsigned cvt_pk_bf16(float lo, float hi) {
  unsigned r;
  asm("v_cvt_pk_bf16_f32 %0, %1, %2" : "=v"(r) : "v"(lo), "v"(hi));
  return r;
}
__device__ __forceinline__ float fexp2(float x) {
  float r;
  asm("v_exp_f32 %0, %1" : "=v"(r) : "v"(x));
  return r;
}

__device__ __forceinline__ void gload16(const void* g, void* l) {
  __builtin_amdgcn_global_load_lds(
      (const __attribute__((address_space(1))) unsigned int*)g,
      (__attribute__((address_space(3))) unsigned int*)l, 16, 0, 0);
}

#define VM_WAIT(n) asm volatile("s_waitcnt vmcnt(" #n ")" ::: "memory")
#define BAR() asm volatile("s_barrier" ::: "memory")
#define PRIO(n) __builtin_amdgcn_s_setprio(n)

#define MFMA16(a, b, c) __builtin_amdgcn_mfma_f32_16x16x32_bf16((a), (b), (c), 0, 0, 0)
#define MFMA32(a, b, c) __builtin_amdgcn_mfma_f32_32x32x16_bf16((a), (b), (c), 0, 0, 0)

// ---- fused front-end: convert_x + convert_w_t + prep ---------------------
__global__ void prepare_all(const float* __restrict__ x, u16* __restrict__ xb,
                            const float* wq, const float* wk, const float* wv,
                            const float* wo, u16* qkvT, u16* woT,
                            const float* ps, const float* wmod, const float* bmod,
                            float* out_tail, float* scale_buf, float* diag_buf) {
  int bid = blockIdx.x;
  int tid = threadIdx.x;
  if (bid < 4096) {
    int i = bid * 256 + tid;
    float4 v = ((const float4*)x)[i];
    ushort4 o;
    o.x = f2bf(v.x); o.y = f2bf(v.y); o.z = f2bf(v.z); o.w = f2bf(v.w);
    ((ushort4*)xb)[i] = o;
    return;
  }
  if (bid < 5120) {
    int inner = bid - 4096;
    int z = inner >> 8;
    int rem = inner & 255;
    int k0 = (rem & 15) * 64, n0 = (rem >> 4) * 64;
    const float* w = (z == 0) ? wq : (z == 1) ? wk : (z == 2) ? wv : wo;
    u16* wt = (z == 3) ? woT : qkvT + (size_t)z * 1024 * 1024;
    __shared__ float tile[64][65];
    int r = tid >> 4, c = (tid & 15) * 4;
#pragma unroll
    for (int i = 0; i < 4; i++) {
      float4 v = *(const float4*)(w + (size_t)(k0 + r + i * 16) * 1024 + n0 + c);
      tile[r + i * 16][c] = v.x; tile[r + i * 16][c + 1] = v.y;
      tile[r + i * 16][c + 2] = v.z; tile[r + i * 16][c + 3] = v.w;
    }
    __syncthreads();
#pragma unroll
    for (int i = 0; i < 4; i++) {
      int rn = r + i * 16;
      ushort4 o;
      o.x = f2bf(tile[c][rn]); o.y = f2bf(tile[c + 1][rn]);
      o.z = f2bf(tile[c + 2][rn]); o.w = f2bf(tile[c + 3][rn]);
      *(ushort4*)(wt + (size_t)(n0 + rn) * 1024 + k0 + c) = o;
    }
    return;
  }
  if (tid < B_ * H_) {
    int b = tid >> 4, h = tid & 15;
    float p = ps[b];
    float m0 = p * wmod[2 * h] + bmod[2 * h];
    float m1 = p * wmod[2 * h + 1] + bmod[2 * h + 1];
    float sp = (m0 > 20.f) ? m0 : log1pf(expf(m0));
    float temp = 1.f + sp;
    out_tail[tid] = temp;
    scale_buf[tid] = LOG2E / (8.f * temp);
    diag_buf[tid] = m1 * LOG2E;
  }
}

// ---- fused QKV GEMM (ring-3, 2-barrier, counted vmcnt, LDS XOR swizzle) --
__global__ __launch_bounds__(256) void gemm_qkv(const u16* __restrict__ A, const u16* __restrict__ BT,
                                                const float* __restrict__ bq, const float* __restrict__ bk,
                                                const float* __restrict__ bv,
                                                const float* __restrict__ scale_buf,
                                                u16* __restrict__ Cout) {
  __shared__ u16 As[3][128 * 32];
  __shared__ u16 Bs[3][128 * 32];
  int m0 = blockIdx.x * 128, n0 = blockIdx.y * 128;
  int tid = threadIdx.x;
  int w = tid >> 6, l = tid & 63;
  int wr = w >> 1, wc = w & 1;
  int lrow = l & 15, kb = l >> 4;
  int r = tid >> 2, c = tid & 3;
  // pre-swizzled global source (slot' = c ^ (row&3)); LDS dest stays linear
  int cs = (c ^ (r & 3)) * 8;
  f32x4 acc[4][4] = {};

#define GQ_STAGE(buf, k0g)                                                                  \
  {                                                                                         \
    _Pragma("unroll") for (int j = 0; j < 2; j++) {                                         \
      gload16(A + (size_t)(m0 + r + j * 64) * C_ + (k0g) + cs,                              \
              (char*)As[buf] + (r + j * 64) * 64 + c * 16);                                 \
      gload16(BT + (size_t)(n0 + r + j * 64) * C_ + (k0g) + cs,                             \
              (char*)Bs[buf] + (r + j * 64) * 64 + c * 16);                                 \
    }                                                                                       \
  }

#define GQ_COMPUTE(BUF)                                                                     \
  {                                                                                         \
    const u16* Ac = As[BUF];                                                                \
    const u16* Bc = Bs[BUF];                                                                \
    int kslot = (kb ^ (lrow & 3)) * 8;                                                      \
    bf16x8 af[4], bfv[4];                                                                   \
    _Pragma("unroll") for (int mi = 0; mi < 4; mi++)                                        \
        af[mi] = *(const bf16x8*)(Ac + (wr * 64 + mi * 16 + lrow) * 32 + kslot);            \
    _Pragma("unroll") for (int ni = 0; ni < 4; ni++)                                        \
        bfv[ni] = *(const bf16x8*)(Bc + (wc * 64 + ni * 16 + lrow) * 32 + kslot);           \
    _Pragma("unroll") for (int mi = 0; mi < 4; mi++)                                        \
        _Pragma("unroll") for (int ni = 0; ni < 4; ni++)                                    \
            acc[mi][ni] = MFMA16(af[mi], bfv[ni], acc[mi][ni]);                             \
  }

  GQ_STAGE(0, 0);
  GQ_STAGE(1, 32);
  int buf = 0;
  for (int i = 0; i < 30; i++) {
    int nbuf = (buf + 2) % 3;
    GQ_STAGE(nbuf, (i + 2) * 32);
    VM_WAIT(8);
    BAR();
    GQ_COMPUTE(buf);
    BAR();
    buf = (buf + 1) % 3;
  }
  VM_WAIT(4);
  BAR();
  GQ_COMPUTE(buf);
  buf = (buf + 1) % 3;
  VM_WAIT(0);
  BAR();
  GQ_COMPUTE(buf);
#undef GQ_STAGE
#undef GQ_COMPUTE

  int bb = m0 >> 11;
#pragma unroll
  for (int mi = 0; mi < 4; mi++)
#pragma unroll
    for (int ni = 0; ni < 4; ni++) {
      int gcol = n0 + wc * 64 + ni * 16 + lrow;
      int sect = gcol >> 10;
      const float* bp = (sect == 0) ? bq : (sect == 1) ? bk : bv;
      float bvf = bp[gcol & 1023];
      float fac = (sect == 0) ? scale_buf[bb * 16 + ((gcol >> 6) & 15)] : 1.f;
#pragma unroll
      for (int rr = 0; rr < 4; rr++) {
        int grow = m0 + wr * 64 + mi * 16 + kb * 4 + rr;
        Cout[(size_t)grow * QLD + gcol] = f2bf((acc[mi][ni][rr] + bvf) * fac);
      }
    }
}

// ---- out-projection GEMM (ring-3, 2-barrier, LDS XOR swizzle), f32 out ---
__global__ __launch_bounds__(256) void gemm_bt_f32(const u16* __restrict__ A, const u16* __restrict__ BT,
                                                   const float* __restrict__ bias,
                                                   float* __restrict__ Cout) {
  __shared__ u16 As[3][128 * 32];
  __shared__ u16 Bs[3][128 * 32];
  int m0 = blockIdx.x * 128, n0 = blockIdx.y * 128;
  int tid = threadIdx.x;
  int w = tid >> 6, l = tid & 63;
  int wr = w >> 1, wc = w & 1;
  int lrow = l & 15, kb = l >> 4;
  int r = tid >> 2, c = tid & 3;
  int cs = (c ^ (r & 3)) * 8;
  f32x4 acc[4][4] = {};

#define GB_STAGE(buf, k0g)                                                                  \
  {                                                                                         \
    _Pragma("unroll") for (int j = 0; j < 2; j++) {                                         \
      gload16(A + (size_t)(m0 + r + j * 64) * C_ + (k0g) + cs,                              \
              (char*)As[buf] + (r + j * 64) * 64 + c * 16);                                 \
      gload16(BT + (size_t)(n0 + r + j * 64) * C_ + (k0g) + cs,                             \
              (char*)Bs[buf] + (r + j * 64) * 64 + c * 16);                                 \
    }                                                                                       \
  }

#define GB_COMPUTE(BUF)                                                                     \
  {                                                                                         \
    const u16* Ac = As[BUF];                                                                \
    const u16* Bc = Bs[BUF];                                                                \
    int kslot = (kb ^ (lrow & 3)) * 8;                                                      \
    bf16x8 af[4], bfv[4];                                                                   \
    _Pragma("unroll") for (int mi = 0; mi < 4; mi++)                                        \
        af[mi] = *(const bf16x8*)(Ac + (wr * 64 + mi * 16 + lrow) * 32 + kslot);            \
    _Pragma("unroll") for (int ni = 0; ni < 4; ni++)                                        \
        bfv[ni] = *(const bf16x8*)(Bc + (wc * 64 + ni * 16 + lrow) * 32 + kslot);           \
    _Pragma("unroll") for (int mi = 0; mi < 4; mi++)                                        \
        _Pragma("unroll") for (int ni = 0; ni < 4; ni++)                                    \
            acc[mi][ni] = MFMA16(af[mi], bfv[ni], acc[mi][ni]);                             \
  }

  GB_STAGE(0, 0);
  GB_STAGE(1, 32);
  int buf = 0;
  for (int i = 0; i < 30; i++) {
    int nbuf = (buf + 2) % 3;
    GB_STAGE(nbuf, (i + 2) * 32);
    VM_WAIT(8);
    BAR();
    GB_COMPUTE(buf);
    BAR();
    buf = (buf + 1) % 3;
  }
  VM_WAIT(4);
  BAR();
  GB_COMPUTE(buf);
  buf = (buf + 1) % 3;
  VM_WAIT(0);
  BAR();
  GB_COMPUTE(buf);
#undef GB_STAGE
#undef GB_COMPUTE

#pragma unroll
  for (int mi = 0; mi < 4; mi++)
#pragma unroll
    for (int ni = 0; ni < 4; ni++) {
      int gcol = n0 + wc * 64 + ni * 16 + lrow;
      float bvf = bias[gcol];
#pragma unroll
      for (int rr = 0; rr < 4; rr++) {
        int grow = m0 + wr * 64 + mi * 16 + kb * 4 + rr;
        Cout[(size_t)grow * C_ + gcol] = acc[mi][ni][rr] + bvf;
      }
    }
}

// ---- pass 1: partial l[s] (8 waves, ring-4 Q prefetch, counted vmcnt) ----
__global__ __launch_bounds__(512) void attn_pass1(const u16* __restrict__ q, const u16* __restrict__ k,
                                                  const int* __restrict__ mask,
                                                  const float* __restrict__ diag_buf,
                                                  float* __restrict__ l_part) {
  __shared__ u16 Qs[4][64 * 64];
  int bh = blockIdx.x, b = bh >> 4, h = bh & 15;
  int s0b = blockIdx.y * 256;
  int half = blockIdx.z;
  int tid = threadIdx.x, w = tid >> 6, l = tid & 63;
  int lane31 = l & 31, hi = l >> 5;
  float diagb = diag_buf[bh];
  int s_wb = s0b + w * 32;
  int s_g = s_wb + lane31;
  bool dhit = (((l >> 2) & 1) == hi);
  int dreg = (l & 3) + 4 * ((l >> 3) & 3);
  int sr = tid >> 3, slotL = tid & 7;
  int slotG = slotL ^ (sr & 7);
  bf16x8 kf[4];
#pragma unroll
  for (int ks = 0; ks < 4; ks++)
    kf[ks] = *(const bf16x8*)(k + (size_t)(b * T_ + s_g) * QLD + h * 64 + ks * 16 + hi * 8);

  int tbase = half * 1024;
#define STAGE_Q(buf, t0g)                                                     \
  gload16(q + (size_t)(b * T_ + (t0g) + sr) * QLD + h * 64 + slotG * 8,       \
          (char*)Qs[buf] + sr * 128 + slotL * 16)

#define P1_COMPUTE(IT)                                                        \
  {                                                                           \
    const u16* Qc = Qs[(IT) & 3];                                             \
    int t0 = tbase + (IT) * 64;                                               \
    _Pragma("unroll") for (int sub = 0; sub < 2; sub++) {                     \
      int tloc = sub * 32;                                                    \
      f32x16 sacc = {};                                                       \
      PRIO(1);                                                                \
      _Pragma("unroll") for (int ks = 0; ks < 4; ks++) {                      \
        int row = tloc + lane31;                                              \
        int slot = (ks * 2 + hi) ^ (row & 7);                                 \
        bf16x8 qa = *(const bf16x8*)(Qc + row * 64 + slot * 8);               \
        sacc = MFMA32(qa, kf[ks], sacc);                                      \
      }                                                                       \
      PRIO(0);                                                                \
      if (t0 + tloc == s_wb) {                                                \
        _Pragma("unroll") for (int r = 0; r < 16; r++)                        \
            sacc[r] += (dhit && r == dreg) ? diagb : 0.f;                     \
      }                                                                       \
      int mv = mask[b * T_ + t0 + tloc + lane31];                             \
      bool allset = (~__ballot(mv != 0)) == 0ull;                             \
      if (allset) {                                                           \
        _Pragma("unroll") for (int r = 0; r < 16; r++) lsum += fexp2(sacc[r]); \
      } else {                                                                \
        float mvf = mv ? 1.f : 0.f;                                           \
        _Pragma("unroll") for (int r = 0; r < 16; r++) {                      \
          float mp = __shfl(mvf, (r & 3) + 8 * (r >> 2) + 4 * hi, 64);        \
          lsum += mp * fexp2(sacc[r]);                                        \
        }                                                                     \
      }                                                                       \
    }                                                                         \
  }

  float lsum = 0.f;
  STAGE_Q(0, tbase);
  STAGE_Q(1, tbase + 64);
  for (int it = 0; it < 14; it++) {
    STAGE_Q((it + 2) & 3, tbase + (it + 2) * 64);
    VM_WAIT(2);
    BAR();
    P1_COMPUTE(it);
  }
  VM_WAIT(1);
  BAR();
  P1_COMPUTE(14);
  VM_WAIT(0);
  BAR();
  P1_COMPUTE(15);
  float total = lsum + __shfl_xor(lsum, 32, 64);
  if (hi == 0) l_part[half * (32 * 2048) + bh * 2048 + s_g] = total;
#undef STAGE_Q
#undef P1_COMPUTE
}

// ---- v scaled by 1/l, transposed -> vT -----------------------------------
__global__ void scale_transpose_v(const u16* __restrict__ qkv, const float* __restrict__ l_part,
                                  u16* __restrict__ vT) {
  __shared__ float tile[64][65];
  int st0 = blockIdx.x * 64;
  int hd0 = blockIdx.y * 64;
  int tid = threadIdx.x;
  int r = tid >> 4, c4 = (tid & 15) * 4;
#pragma unroll
  for (int i = 0; i < 4; i++) {
    int row = r + i * 16;
    ushort4 hh = *(const ushort4*)(qkv + (size_t)(st0 + row) * QLD + 2048 + hd0 + c4);
    tile[row][c4] = bf2f(hh.x); tile[row][c4 + 1] = bf2f(hh.y);
    tile[row][c4 + 2] = bf2f(hh.z); tile[row][c4 + 3] = bf2f(hh.w);
  }
  __syncthreads();
  int b = st0 >> 11, sbase = st0 & 2047, h = hd0 >> 6, bh = b * 16 + h;
#pragma unroll
  for (int i = 0; i < 4; i++) {
    int dl = r + i * 16;
    ushort4 o4;
#pragma unroll
    for (int j = 0; j < 4; j++) {
      int s = sbase + c4 + j;
      float il = 1.f / (l_part[bh * 2048 + s] + l_part[32 * 2048 + bh * 2048 + s]);
      ((u16*)&o4)[j] = f2bf(tile[c4 + j][dl] * il);
    }
    *(ushort4*)(vT + (size_t)(bh * 64 + dl) * T_ + sbase + c4) = o4;
  }
}

// ---- pass 2 (8 waves, s-split x2, ring-4 K/V, counted vmcnt, setprio) ----
__global__ __launch_bounds__(512) void attn_pass2(const u16* __restrict__ q, const u16* __restrict__ k,
                                                  const u16* __restrict__ vT,
                                                  const int* __restrict__ mask,
                                                  const float* __restrict__ diag_buf,
                                                  u16* __restrict__ obp) {
  __shared__ u16 Ks[4][64 * 64];
  __shared__ u16 Vs[4][64 * 64];
  int bh = blockIdx.x, b = bh >> 4, h = bh & 15;
  int t0 = blockIdx.y * 256;
  int shalf = blockIdx.z;
  int s_start = shalf * 1024;
  u16* op = obp + (size_t)shalf * 4096 * 1024;
  int tid = threadIdx.x, w = tid >> 6, l = tid & 63;
  int lane31 = l & 31, hi = l >> 5;
  float diagb = diag_buf[bh];
  int t_wb = t0 + w * 32;
  int t_g = t_wb + lane31;
  bool dhit = (((l >> 2) & 1) == hi);
  int dreg = (l & 3) + 4 * ((l >> 3) & 3);
  int sr = tid >> 3, slotL = tid & 7;
  int slotG = slotL ^ (sr & 7);
  bf16x8 qf[4];
#pragma unroll
  for (int ks = 0; ks < 4; ks++)
    qf[ks] = *(const bf16x8*)(q + (size_t)(b * T_ + t_g) * QLD + h * 64 + ks * 16 + hi * 8);
  int mv = mask[b * T_ + t_g];
  float tmf = mv ? 1.f : 0.f;
  bool allset = (~__ballot(mv != 0)) == 0ull;
  f32x16 oacc0 = {}, oacc1 = {};

#define STAGE_KV(buf, s0g)                                                    \
  {                                                                           \
    gload16(k + (size_t)(b * T_ + (s0g) + sr) * QLD + h * 64 + slotG * 8,     \
            (char*)Ks[buf] + sr * 128 + slotL * 16);                          \
    gload16(vT + (size_t)(bh * 64 + sr) * T_ + (s0g) + slotG * 8,             \
            (char*)Vs[buf] + sr * 128 + slotL * 16);                          \
  }

#define P2_COMPUTE(SI)                                                        \
  {                                                                           \
    const u16* Kc = Ks[(SI) & 3];                                             \
    const u16* Vc = Vs[(SI) & 3];                                             \
    int s0 = s_start + (SI) * 64;                                             \
    _Pragma("unroll") for (int sub = 0; sub < 2; sub++) {                     \
      int ss = sub * 32;                                                      \
      f32x16 sacc = {};                                                       \
      PRIO(1);                                                                \
      _Pragma("unroll") for (int ks = 0; ks < 4; ks++) {                      \
        int row = ss + lane31;                                                \
        int slot = (ks * 2 + hi) ^ (row & 7);                                 \
        bf16x8 kfr = *(const bf16x8*)(Kc + row * 64 + slot * 8);              \
        sacc = MFMA32(kfr, qf[ks], sacc);                                     \
      }                                                                       \
      PRIO(0);                                                                \
      if (s0 + ss == t_wb) {                                                  \
        _Pragma("unroll") for (int r = 0; r < 16; r++)                        \
            sacc[r] += (dhit && r == dreg) ? diagb : 0.f;                     \
      }                                                                       \
      float p[16];                                                            \
      _Pragma("unroll") for (int r = 0; r < 16; r++) p[r] = fexp2(sacc[r]);   \
      if (!allset) {                                                          \
        _Pragma("unroll") for (int r = 0; r < 16; r++) p[r] *= tmf;           \
      }                                                                       \
      unsigned pk[8];                                                         \
      _Pragma("unroll") for (int i = 0; i < 8; i++)                           \
          pk[i] = cvt_pk_bf16(p[2 * i], p[2 * i + 1]);                        \
      _Pragma("unroll") for (int ps = 0; ps < 2; ps++) {                      \
        unsigned a0 = pk[4 * ps + 0], a2 = pk[4 * ps + 2];                    \
        unsigned a1 = pk[4 * ps + 1], a3 = pk[4 * ps + 3];                    \
        asm("v_permlane32_swap_b32 %0, %1" : "+v"(a0), "+v"(a2));             \
        asm("v_permlane32_swap_b32 %0, %1" : "+v"(a1), "+v"(a3));             \
        union { unsigned u[4]; bf16x8 v; } fr;                                \
        fr.u[0] = a0; fr.u[1] = a1; fr.u[2] = a2; fr.u[3] = a3;               \
        PRIO(1);                                                              \
        _Pragma("unroll") for (int dh = 0; dh < 2; dh++) {                    \
          int row = dh * 32 + lane31;                                         \
          int slot = ((ss >> 3) + ps * 2 + hi) ^ (row & 7);                   \
          bf16x8 vfr = *(const bf16x8*)(Vc + row * 64 + slot * 8);            \
          if (dh == 0) oacc0 = MFMA32(fr.v, vfr, oacc0);                      \
          else oacc1 = MFMA32(fr.v, vfr, oacc1);                              \
        }                                                                     \
        PRIO(0);                                                              \
      }                                                                       \
    }                                                                         \
  }

  STAGE_KV(0, s_start);
  STAGE_KV(1, s_start + 64);
  for (int si = 0; si < 14; si++) {
    STAGE_KV((si + 2) & 3, s_start + (si + 2) * 64);
    VM_WAIT(4);
    BAR();
    P2_COMPUTE(si);
  }
  VM_WAIT(2);
  BAR();
  P2_COMPUTE(14);
  VM_WAIT(0);
  BAR();
  P2_COMPUTE(15);
#pragma unroll
  for (int r = 0; r < 16; r++) {
    int t_out = t0 + w * 32 + ((r & 3) + 8 * (r >> 2) + 4 * hi);
    size_t base = (size_t)(b * T_ + t_out) * HD_ + h * 64;
    op[base + lane31] = f2bf(oacc0[r]);
    op[base + 32 + lane31] = f2bf(oacc1[r]);
  }
#undef STAGE_KV
#undef P2_COMPUTE
}

// ---- merge the two s-half partial O buffers ------------------------------
__global__ void merge_o(const u16* __restrict__ p0, const u16* __restrict__ p1,
                        u16* __restrict__ ob) {
  int i = blockIdx.x * 256 + threadIdx.x;
  u16x8 a = ((const u16x8*)p0)[i];
  u16x8 b = ((const u16x8*)p1)[i];
  u16x8 o;
#pragma unroll
  for (int j = 0; j < 8; j++) o[j] = f2bf(bf2f(a[j]) + bf2f(b[j]));
  ((u16x8*)ob)[i] = o;
}

extern "C" void kernel_launch(void* const* d_in, const int* in_sizes, int n_in,
                              void* d_out, int out_size, void* d_ws, size_t ws_size,
                              hipStream_t stream) {
  const float* x = (const float*)d_in[0];
  const int* mask = (const int*)d_in[1];
  const float* ps = (const float*)d_in[2];
  const float* wq = (const float*)d_in[3];
  const float* bq = (const float*)d_in[4];
  const float* wk = (const float*)d_in[5];
  const float* bk = (const float*)d_in[6];
  const float* wv = (const float*)d_in[7];
  const float* bv = (const float*)d_in[8];
  const float* wmod = (const float*)d_in[9];
  const float* bmod = (const float*)d_in[10];
  const float* wo = (const float*)d_in[11];
  const float* bo = (const float*)d_in[12];
  float* out = (float*)d_out;

  const size_t MB = 1ull << 20;
  char* ws = (char*)d_ws;
  u16* xb    = (u16*)(ws + 0 * MB);   // 8 MB
  u16* qkvT  = (u16*)(ws + 8 * MB);   // 6 MB
  u16* woT   = (u16*)(ws + 14 * MB);  // 2 MB
  u16* qkv   = (u16*)(ws + 16 * MB);  // 24 MB
  u16* vT    = (u16*)(ws + 40 * MB);  // 8 MB
  u16* ob    = (u16*)(ws + 48 * MB);  // 8 MB
  float* l_part    = (float*)(ws + 56 * MB);            // 512 KB
  float* scale_buf = (float*)(ws + 56 * MB + 0x80000);  // 128 B
  float* diag_buf  = (float*)(ws + 56 * MB + 0x80100);  // 128 B
  u16* obp   = (u16*)(ws + 64 * MB);  // 16 MB (2 x 8 MB partial O)

  prepare_all<<<5121, 256, 0, stream>>>(x, xb, wq, wk, wv, wo, qkvT, woT,
                                        ps, wmod, bmod, out + (size_t)B_ * T_ * C_,
                                        scale_buf, diag_buf);
  gemm_qkv<<<dim3(32, 24), 256, 0, stream>>>(xb, qkvT, bq, bk, bv, scale_buf, qkv);
  attn_pass1<<<dim3(32, 8, 2), 512, 0, stream>>>(qkv, qkv + 1024, mask, diag_buf, l_part);
  scale_transpose_v<<<dim3(64, 16), 256, 0, stream>>>(qkv, l_part, vT);
  attn_pass2<<<dim3(32, 8, 2), 512, 0, stream>>>(qkv, qkv + 1024, vT, mask, diag_buf, obp);
  merge_o<<<2048, 256, 0, stream>>>(obp, obp + (size_t)4096 * 1024, ob);
  gemm_bt_f32<<<dim3(32, 8), 256, 0, stream>>>(ob, woT, bo, out);
}